// Round 11
// baseline (260.815 us; speedup 1.0000x reference)
//
#include <hip/hip_runtime.h>

typedef __attribute__((ext_vector_type(8))) short short8;
typedef __attribute__((ext_vector_type(4))) float float4v;
typedef __attribute__((ext_vector_type(16))) float float16v;
typedef __attribute__((ext_vector_type(4))) unsigned short ushort4v;

#define NB 32
#define NC 512
#define NL 512
#define NH 8
#define NDK 64

__device__ __forceinline__ unsigned short f2b(float f) {
  union { float f; unsigned int u; } v; v.f = f;
  unsigned int r = v.u + 0x7FFFu + ((v.u >> 16) & 1u);
  return (unsigned short)(r >> 16);
}

__device__ __forceinline__ void gld16(const void* g, void* l) {
  __builtin_amdgcn_global_load_lds(
      (const __attribute__((address_space(1))) unsigned int*)g,
      (__attribute__((address_space(3))) unsigned int*)l, 16, 0, 0);
}

__device__ __forceinline__ float4v bmfma(short8 a, short8 b, float4v c) {
  return __builtin_amdgcn_mfma_f32_16x16x32_bf16(a, b, c, 0, 0, 0);
}

// ---- fused prep: depthwise conv(7) with inline posconv for q,k; plus -------
// ---- fp32->bf16 weight conversion absorbed as extra z-slices ---------------
// dw core: c64 x l64 tile, one barrier, 6144 independent blocks.
// gld16 staging: LDS dest is WAVE-UNIFORM base + lane*16 (m104), so every
// wave is fully active -- all 1344 cells (incl. pad f4==20 and OOB halo)
// issue gld16 with a CLAMPED global address. Pad garbage never read; OOB
// halo garbage zeroed in registers (wave-uniform branches on edge blocks).
// Stride 84 == 20 mod 32 keeps the 64-lane b128 compute reads conflict-free.
__global__ __launch_bounds__(256) void dw_kernel(
    const float* __restrict__ q, const float* __restrict__ k, const float* __restrict__ v,
    const float* __restrict__ pos,
    const float* __restrict__ qw, const float* __restrict__ kw, const float* __restrict__ vw,
    const float* __restrict__ qb2, const float* __restrict__ kb2, const float* __restrict__ vb,
    const float* __restrict__ cq, const float* __restrict__ ck,
    const float* __restrict__ cv, const float* __restrict__ cp,
    unsigned short* __restrict__ wq, unsigned short* __restrict__ wk,
    unsigned short* __restrict__ wv, unsigned short* __restrict__ wp,
    unsigned short* __restrict__ yq, unsigned short* __restrict__ yk,
    unsigned short* __restrict__ yv) {
  int z = blockIdx.z;
  int tid = threadIdx.x;
  if (z >= 96) {
    // ---- cvt4 job: fp32 -> bf16, 4 matrices of 512x512 ----
    int idx = (z - 96) * 64 + blockIdx.y * 8 + blockIdx.x;
    int m = idx >> 8, blk = idx & 255;
    const float* src = (m == 0) ? cq : (m == 1) ? ck : (m == 2) ? cv : cp;
    unsigned short* dst = (m == 0) ? wq : (m == 1) ? wk : (m == 2) ? wv : wp;
    int i = (blk * 256 + tid) * 4;
    float4v vv = *(const float4v*)(src + i);
    ushort4v o;
    o.x = f2b(vv.x); o.y = f2b(vv.y); o.z = f2b(vv.z); o.w = f2b(vv.w);
    *(ushort4v*)(dst + i) = o;
    return;
  }
  int t = z >> 5, b = z & 31;
  const float* x   = (t == 0) ? q  : (t == 1) ? k  : v;
  const float* dww = (t == 0) ? qw : (t == 1) ? kw : vw;
  const float* dwb = (t == 0) ? qb2 : (t == 1) ? kb2 : vb;
  unsigned short* yT = (t == 0) ? yq : (t == 1) ? yk : yv;
  int c0 = blockIdx.y * 64, l0 = blockIdx.x * 64;
  __shared__ __attribute__((aligned(16))) float xs[64 * 84];
#pragma unroll
  for (int it = 0; it < 6; ++it) {
    int idx = tid + 256 * it;
    if (idx < 1344) {
      int row = idx / 21, f4 = idx - row * 21;
      int l = l0 - 8 + f4 * 4;
      int lc = l < 0 ? 0 : (l > NL - 4 ? NL - 4 : l);
      gld16(x + ((size_t)b * NC + c0 + row) * NL + lc, xs + idx * 4);
    }
  }
  int cl = tid & 63;
  int llb = (tid >> 6) * 16;
  int c = c0 + cl;
  // hoisted independent work: taps, bias, inline posconv (hides under staging)
  float wt[7];
#pragma unroll
  for (int tt = 0; tt < 7; ++tt) wt[tt] = dww[c * 7 + tt];
  float bias0 = dwb[c];
  float addv[16];
  if (t < 2) {
    // addv[i] = dwb[c] + sum_tt pos[l0+llb+i+tt-3, c] * wt[tt]
    float pv[22];
#pragma unroll
    for (int j = 0; j < 22; ++j) {
      int ll = l0 + llb - 3 + j;
      pv[j] = ((unsigned)ll < (unsigned)NL) ? pos[(size_t)ll * NC + c] : 0.f;
    }
#pragma unroll
    for (int i = 0; i < 16; ++i) {
      float acc = bias0;
#pragma unroll
      for (int tt = 0; tt < 7; ++tt) acc += pv[i + tt] * wt[tt];
      addv[i] = acc;
    }
  } else {
#pragma unroll
    for (int i = 0; i < 16; ++i) addv[i] = bias0;
  }
  __syncthreads();
  // per-thread window: w[j] = x[l0 + llb - 4 + j], j = 0..23
  float w[24];
  const float4v* xr = (const float4v*)(xs + cl * 84 + llb + 4);
#pragma unroll
  for (int j = 0; j < 6; ++j) {
    float4v t4 = xr[j];
    w[4 * j] = t4.x; w[4 * j + 1] = t4.y; w[4 * j + 2] = t4.z; w[4 * j + 3] = t4.w;
  }
  // zero the OOB taps (clamped-load garbage); wave-uniform branches.
  if (blockIdx.x == 0 && llb == 0) {
    w[0] = 0.f; w[1] = 0.f; w[2] = 0.f; w[3] = 0.f;
  } else if (blockIdx.x == 7 && llb == 48) {
    w[20] = 0.f; w[21] = 0.f; w[22] = 0.f; w[23] = 0.f;
  }
#pragma unroll
  for (int i = 0; i < 16; ++i) {
    float acc = addv[i];
#pragma unroll
    for (int tt = 0; tt < 7; ++tt) acc += w[i + 1 + tt] * wt[tt];
    yT[((size_t)b * NL + l0 + llb + i) * NC + c] = f2b(acc);
  }
}

// ---- 128x128 MFMA GEMM core, BK=64, global-XOR-swizzled staging ------------
__device__ __forceinline__ void gemm_core_bk64(
    const unsigned short* __restrict__ A, const unsigned short* __restrict__ B,
    unsigned short* lA, unsigned short* lB, float4v acc[4][4], int m0, int n0) {
  int tid = threadIdx.x;
  int lane = tid & 63, quad = lane >> 4, l15 = lane & 15;
  int wave = tid >> 6, wr = wave >> 1, wc = wave & 1;
  const unsigned short* gA[4];
  const unsigned short* gB[4];
  unsigned short* dA[4];
  unsigned short* dB[4];
#pragma unroll
  for (int i = 0; i < 4; ++i) {
    int cc = tid + 256 * i;
    int row = cc >> 3;
    int gc = (cc & 7) ^ (row & 7);
    gA[i] = A + (size_t)(m0 + row) * 512 + gc * 8;
    gB[i] = B + (size_t)(n0 + row) * 512 + gc * 8;
    dA[i] = lA + cc * 8;
    dB[i] = lB + cc * 8;
  }
  for (int k0 = 0; k0 < 512; k0 += 64) {
#pragma unroll
    for (int i = 0; i < 4; ++i) gld16(gA[i] + k0, dA[i]);
#pragma unroll
    for (int i = 0; i < 4; ++i) gld16(gB[i] + k0, dB[i]);
    __syncthreads();
#pragma unroll
    for (int ks = 0; ks < 2; ++ks) {
      int sw = (ks * 4 + quad) ^ (l15 & 7);
      short8 af[4], bf[4];
#pragma unroll
      for (int mt = 0; mt < 4; ++mt)
        af[mt] = *(const short8*)(lA + (wr * 64 + mt * 16 + l15) * 64 + sw * 8);
#pragma unroll
      for (int nt = 0; nt < 4; ++nt)
        bf[nt] = *(const short8*)(lB + (wc * 64 + nt * 16 + l15) * 64 + sw * 8);
#pragma unroll
      for (int mt = 0; mt < 4; ++mt)
#pragma unroll
        for (int nt = 0; nt < 4; ++nt)
          acc[mt][nt] = bmfma(af[mt], bf[nt], acc[mt][nt]);
    }
    __syncthreads();
  }
}

// ---- fused pointwise GEMMs for q,k,v ---------------------------------------
// q output is pre-scaled by 0.125*log2(e) so attention can use exp2 directly.
// q/k epilogue: LDS transpose in [n][m] layout, XOR-swizzled m-index
// (scalar writes keep live ranges short -> ~108 VGPR).
// v epilogue: DIRECT scalar stores (R9 lesson: the LDS-transpose variant
// raised VGPR 108->124 and cost ~9us on this latency-bound GEMM).
__global__ __launch_bounds__(256) void pw_gemm_kernel(
    const unsigned short* __restrict__ wqm, const unsigned short* __restrict__ wkm,
    const unsigned short* __restrict__ wvm,
    const unsigned short* __restrict__ yq, const unsigned short* __restrict__ yk,
    const unsigned short* __restrict__ yv,
    const float* __restrict__ qb, const float* __restrict__ kb, const float* __restrict__ vb,
    unsigned short* __restrict__ qT, unsigned short* __restrict__ kT,
    unsigned short* __restrict__ vvo) {
  int z = blockIdx.z, t = z >> 5, b = z & 31;
  const unsigned short* W = (t == 0) ? wqm : (t == 1) ? wkm : wvm;
  const unsigned short* Y = ((t == 0) ? yq : (t == 1) ? yk : yv) + (size_t)b * NL * NC;
  const float* bias = (t == 0) ? qb : (t == 1) ? kb : vb;
  unsigned short* out = (t == 0) ? qT : (t == 1) ? kT : vvo;
  float oscale = (t == 0) ? 0.18033688011112042f : 1.0f;  // 0.125*log2(e) folded into q
  __shared__ __attribute__((aligned(16))) unsigned short buf[16384];
  unsigned short* lA = buf;
  unsigned short* lB = buf + 8192;
  int m0 = blockIdx.y * 128, n0 = blockIdx.x * 128;
  float4v acc[4][4];
#pragma unroll
  for (int i = 0; i < 4; ++i)
#pragma unroll
    for (int j = 0; j < 4; ++j) acc[i][j] = (float4v){0.f, 0.f, 0.f, 0.f};
  gemm_core_bk64(W, Y, lA, lB, acc, m0, n0);
  int tid = threadIdx.x;
  int lane = tid & 63, quad = lane >> 4, l15 = lane & 15;
  int wave = tid >> 6, wr = wave >> 1, wc = wave & 1;
  if (t < 2) {
    // transpose epilogue through LDS: scalar writes, XOR-swizzled m-index;
    // read side inverts with dc ^ (l&7).
#pragma unroll
    for (int mt = 0; mt < 4; ++mt) {
      int mloc = wr * 64 + mt * 16 + quad * 4;
#pragma unroll
      for (int nt = 0; nt < 4; ++nt) {
        int nloc = wc * 64 + nt * 16 + l15;
        int sx = (nloc & 7) << 3;
#pragma unroll
        for (int r = 0; r < 4; ++r) {
          int ml = mloc + r;
          buf[(ml >> 6) * 8192 + nloc * 64 + ((ml & 63) ^ sx)] =
              f2b((acc[mt][nt][r] + bias[m0 + ml]) * oscale);
        }
      }
    }
    __syncthreads();
#pragma unroll
    for (int it = 0; it < 8; ++it) {
      int cc = tid + it * 256;
      int hloc = cc >> 10, l = (cc >> 3) & 127, dc = cc & 7;
      short8 vd = *(const short8*)(buf + hloc * 8192 + l * 64 + ((dc ^ (l & 7)) << 3));
      *(short8*)(out + (((size_t)b * NH + (m0 >> 6) + hloc) * NL + n0 + l) * NDK + dc * 8) = vd;
    }
  } else {
#pragma unroll
    for (int mt = 0; mt < 4; ++mt)
#pragma unroll
      for (int nt = 0; nt < 4; ++nt) {
        int n = n0 + wc * 64 + nt * 16 + l15;
#pragma unroll
        for (int r = 0; r < 4; ++r) {
          int m = m0 + wr * 64 + mt * 16 + quad * 4 + r;
          out[((size_t)b * NC + m) * NL + n] = f2b(acc[mt][nt][r] + bias[m]);
        }
      }
  }
}

// ---- persistent attention, swapped-QK^T, P fully in-register ---------------
// Compute S^T = mfma(K,Q) so each lane owns one i-COLUMN; P packs to bf16
// in-register (f2b pairs), halves exchange via shfl_xor(32), PV B-fragment
// built by per-half select -> NO P LDS buffer. Row sums: 16 lane-local adds
// + one shfl_xor(32). LDS = Kt+Vt = 128KB -> 512-thread 8-wave block fits
// -> 2 waves/SIMD.
__global__ __launch_bounds__(512, 1) void attn_kernel(
    const unsigned short* __restrict__ qT,  // (B,H,L,DK)
    const unsigned short* __restrict__ kT,  // (B,H,L,DK)
    const unsigned short* __restrict__ vv,  // (B,C,L)
    unsigned short* __restrict__ AO) {      // (B,C,L)
  int bh = blockIdx.x, b = bh >> 3, h = bh & 7;
  int tid = threadIdx.x, lane = tid & 63;
  int l31 = lane & 31, lh = lane >> 5;
  int wave = tid >> 6;
  __shared__ __attribute__((aligned(16))) unsigned short Kt[512 * 64];  // [j][d] swz
  __shared__ __attribute__((aligned(16))) unsigned short Vt[64 * 512];  // [d][j] swz
  const unsigned short* qh = qT + (size_t)bh * NL * NDK;
  const unsigned short* kh = kT + (size_t)bh * NL * NDK;
  const unsigned short* vh = vv + ((size_t)b * NC + h * NDK) * NL;

  // one-time stage of all K and V (swizzle realized on the global side)
#pragma unroll
  for (int ii = 0; ii < 8; ++ii) {
    int cc = tid + 512 * ii;
    int row = cc >> 3, c = (cc & 7) ^ (row & 7);
    gld16(kh + (size_t)row * NDK + c * 8, &Kt[cc * 8]);
  }
#pragma unroll
  for (int ii = 0; ii < 8; ++ii) {
    int cc = tid + 512 * ii;
    int d = cc >> 6, pc = cc & 63;
    int c = (pc & ~7) | ((pc & 7) ^ (d & 7));
    gld16(vh + (size_t)d * NL + c * 8, &Vt[cc * 8]);
  }
  __syncthreads();  // only barrier in the kernel

#pragma unroll
  for (int iset = 0; iset < 2; ++iset) {
    int i0 = wave * 64 + iset * 32;
    // Q as B-operand: n = i = i0 + l31, k = d = s*16 + lh*8 + e
    short8 a[4];
#pragma unroll
    for (int s = 0; s < 4; ++s)
      a[s] = *(const short8*)(qh + (size_t)(i0 + l31) * NDK + s * 16 + lh * 8);
    float16v o0, o1;
#pragma unroll
    for (int r = 0; r < 16; ++r) { o0[r] = 0.f; o1[r] = 0.f; }
    float lsum = 0.f;

    for (int jb = 0; jb < 16; ++jb) {
      // S^T = mfma(K, Q): D[m=j][n=i]; lane owns column i, regs span 32 j
      float16v sacc;
#pragma unroll
      for (int r = 0; r < 16; ++r) sacc[r] = 0.f;
#pragma unroll
      for (int s = 0; s < 4; ++s) {
        int cslot = (s * 2 + lh) ^ (l31 & 7);
        short8 kbf = *(const short8*)(&Kt[(size_t)(jb * 32 + l31) * 64 + cslot * 8]);
        sacc = __builtin_amdgcn_mfma_f32_32x32x16_bf16(kbf, a[s], sacc, 0, 0, 0);
      }
      // p = exp2(s); per-lane row-sum partial (all 16 regs belong to col i)
      float p[16];
#pragma unroll
      for (int r = 0; r < 16; ++r) {
        p[r] = __builtin_amdgcn_exp2f(sacc[r]);
        lsum += p[r];
      }
      // pack to bf16 pairs; reg r holds j_local = (r&3)+8*(r>>2)+4*lh
      unsigned int c0 = (unsigned)f2b(p[0])  | ((unsigned)f2b(p[1])  << 16);  // j {0,1}+4lh
      unsigned int c1 = (unsigned)f2b(p[2])  | ((unsigned)f2b(p[3])  << 16);  // j {2,3}+4lh
      unsigned int c2 = (unsigned)f2b(p[4])  | ((unsigned)f2b(p[5])  << 16);  // j {8,9}+4lh
      unsigned int c3 = (unsigned)f2b(p[6])  | ((unsigned)f2b(p[7])  << 16);  // j {10,11}+4lh
      unsigned int c4 = (unsigned)f2b(p[8])  | ((unsigned)f2b(p[9])  << 16);  // j {16,17}+4lh
      unsigned int c5 = (unsigned)f2b(p[10]) | ((unsigned)f2b(p[11]) << 16);  // j {18,19}+4lh
      unsigned int c6 = (unsigned)f2b(p[12]) | ((unsigned)f2b(p[13]) << 16);  // j {24,25}+4lh
      unsigned int c7 = (unsigned)f2b(p[14]) | ((unsigned)f2b(p[15]) << 16);  // j {26,27}+4lh
      unsigned int q0 = __shfl_xor(c0, 32);
      unsigned int q1 = __shfl_xor(c1, 32);
      unsigned int q2 = __shfl_xor(c2, 32);
      unsigned int q3 = __shfl_xor(c3, 32);
      unsigned int q4 = __shfl_xor(c4, 32);
      unsigned int q5 = __shfl_xor(c5, 32);
      unsigned int q6 = __shfl_xor(c6, 32);
      unsigned int q7 = __shfl_xor(c7, 32);
      // B-fragment for PV: lane needs k = j = js*16 + lh*8 + e
      union { unsigned int u[4]; short8 s8; } f0, f1;
      f0.u[0] = lh ? q2 : c0;  f0.u[1] = lh ? q3 : c1;
      f0.u[2] = lh ? c2 : q0;  f0.u[3] = lh ? c3 : q1;
      f1.u[0] = lh ? q6 : c4;  f1.u[1] = lh ? q7 : c5;
      f1.u[2] = lh ? c6 : q4;  f1.u[3] = lh ? c7 : q5;
      // O += V P^T : A = V[d][j] from Vt, B = frag (register-resident)
#pragma unroll
      for (int js = 0; js < 2; ++js) {
        int g = jb * 4 + js * 2 + lh;
        int vc = (g & ~7) | ((g & 7) ^ (l31 & 7));
        short8 av0 = *(const short8*)(&Vt[(size_t)l31 * 512 + vc * 8]);
        short8 av1 = *(const short8*)(&Vt[(size_t)(32 + l31) * 512 + vc * 8]);
        short8 fb = js ? f1.s8 : f0.s8;
        o0 = __builtin_amdgcn_mfma_f32_32x32x16_bf16(av0, fb, o0, 0, 0, 0);
        o1 = __builtin_amdgcn_mfma_f32_32x32x16_bf16(av1, fb, o1, 0, 0, 0);
      }
    }
    // full row sum for column i: own half + partner half
    float tot = lsum + __shfl_xor(lsum, 32);
    float li = __builtin_amdgcn_rcpf(tot);
#pragma unroll
    for (int r = 0; r < 16; ++r) {
      int dr = (r & 3) + 8 * (r >> 2) + 4 * lh;
      AO[((size_t)b * NC + h * NDK + dr) * NL + i0 + l31] = f2b(o0[r] * li);
      AO[((size_t)b * NC + h * NDK + 32 + dr) * NL + i0 + l31] = f2b(o1[r] * li);
    }
  }
}

// ---- final projection GEMM (fp32 out), M=64 x N=128, BK=32 -----------------
// R10 diagnosis: final never profiled but structurally block-starved (512
// blocks = 2/CU on the latency-bound 128x128 core). This variant: 1024
// blocks (4/CU, all co-resident in one dispatch round), 12 KB LDS, 32-fp32
// acc/thread. Swizzle for 4-chunk rows: phys = quad ^ ((row>>1)&3) -- lanes
// l15 and l15+8 share banks -> exactly 2-way = free (m136); staging source
// pre-swizzled with the same involution, LDS dest linear (all 256 threads
// active per gld16 group -- no predication, R7 lesson).
__global__ __launch_bounds__(256) void final_gemm_kernel(
    const unsigned short* __restrict__ AO, const unsigned short* __restrict__ W,
    const float* __restrict__ bias, float* __restrict__ out) {
  int b = blockIdx.z;
  int m0 = blockIdx.y * 64, n0 = blockIdx.x * 128;
  __shared__ __attribute__((aligned(16))) unsigned short buf[6144];  // 12 KB
  unsigned short* lA = buf;          // 64 x 32
  unsigned short* lB = buf + 2048;   // 128 x 32
  const unsigned short* A = AO + (size_t)b * 512 * 512;
  int tid = threadIdx.x;
  int lane = tid & 63, quad = lane >> 4, l15 = lane & 15;
  int wave = tid >> 6;
  // staging assignments (cell = row*4 + physical chunk)
  int rowA = tid >> 2, pA = tid & 3;
  const unsigned short* gA = A + (size_t)(m0 + rowA) * 512 + (pA ^ ((rowA >> 1) & 3)) * 8;
  unsigned short* dA = lA + tid * 8;
  int ccB0 = tid, ccB1 = tid + 256;
  int rowB0 = ccB0 >> 2, rowB1 = ccB1 >> 2;
  const unsigned short* gB0 = W + (size_t)(n0 + rowB0) * 512 + ((ccB0 & 3) ^ ((rowB0 >> 1) & 3)) * 8;
  const unsigned short* gB1 = W + (size_t)(n0 + rowB1) * 512 + ((ccB1 & 3) ^ ((rowB1 >> 1) & 3)) * 8;
  unsigned short* dB0 = lB + ccB0 * 8;
  unsigned short* dB1 = lB + ccB1 * 8;
  float4v acc[4][2];
#pragma unroll
  for (int i = 0; i < 4; ++i)
#pragma unroll
    for (int j = 0; j < 2; ++j) acc[i][j] = (float4v){0.f, 0.f, 0.f, 0.f};
  int sA = (quad ^ ((l15 >> 1) & 3)) * 8;
  for (int k0 = 0; k0 < 512; k0 += 32) {
    gld16(gA + k0, dA);
    gld16(gB0 + k0, dB0);
    gld16(gB1 + k0, dB1);
    __syncthreads();
    short8 af[4], bf[2];
#pragma unroll
    for (int mt = 0; mt < 4; ++mt)
      af[mt] = *(const short8*)(lA + (mt * 16 + l15) * 32 + sA);
#pragma unroll
    for (int nt = 0; nt < 2; ++nt)
      bf[nt] = *(const short8*)(lB + (wave * 32 + nt * 16 + l15) * 32 + sA);
#pragma unroll
    for (int mt = 0; mt < 4; ++mt)
#pragma unroll
      for (int nt = 0; nt < 2; ++nt)
        acc[mt][nt] = bmfma(af[mt], bf[nt], acc[mt][nt]);
    __syncthreads();
  }
#pragma unroll
  for (int mt = 0; mt < 4; ++mt)
#pragma unroll
    for (int nt = 0; nt < 2; ++nt) {
      int n = n0 + wave * 32 + nt * 16 + l15;
      float bn = bias[n];
#pragma unroll
      for (int r = 0; r < 4; ++r) {
        int m = m0 + mt * 16 + quad * 4 + r;
        out[((size_t)b * 512 + m) * 512 + n] = acc[mt][nt][r] + bn;
      }
    }
}

extern "C" void kernel_launch(void* const* d_in, const int* in_sizes, int n_in,
                              void* d_out, int out_size, void* d_ws, size_t ws_size,
                              hipStream_t stream) {
  (void)in_sizes; (void)n_in; (void)out_size; (void)ws_size;
  const float* query  = (const float*)d_in[0];
  const float* key    = (const float*)d_in[1];
  const float* value  = (const float*)d_in[2];
  const float* pos    = (const float*)d_in[3];
  const float* proj_w = (const float*)d_in[4];
  const float* proj_b = (const float*)d_in[5];
  const float* q_dw_w = (const float*)d_in[6];
  const float* q_dw_b = (const float*)d_in[7];
  const float* q_pw_w = (const float*)d_in[8];
  const float* q_pw_b = (const float*)d_in[9];
  const float* k_dw_w = (const float*)d_in[10];
  const float* k_dw_b = (const float*)d_in[11];
  const float* k_pw_w = (const float*)d_in[12];
  const float* k_pw_b = (const float*)d_in[13];
  const float* v_dw_w = (const float*)d_in[14];
  const float* v_dw_b = (const float*)d_in[15];
  const float* v_pw_w = (const float*)d_in[16];
  const float* v_pw_b = (const float*)d_in[17];

  char* ws = (char*)d_ws;
  const size_t WMAT = (size_t)512 * 512 * 2;     // 512 KB
  const size_t TEN  = (size_t)NB * NC * NL * 2;  // 16 MB
  unsigned short* wq  = (unsigned short*)(ws);
  unsigned short* wk  = (unsigned short*)(ws + WMAT);
  unsigned short* wv  = (unsigned short*)(ws + 2 * WMAT);
  unsigned short* wp  = (unsigned short*)(ws + 3 * WMAT);
  unsigned short* yq  = (unsigned short*)(ws + 4 * WMAT);
  unsigned short* yk  = (unsigned short*)(ws + 4 * WMAT + TEN);
  unsigned short* yv  = (unsigned short*)(ws + 4 * WMAT + 2 * TEN);
  unsigned short* qT  = (unsigned short*)(ws + 4 * WMAT + 3 * TEN);
  unsigned short* kT  = (unsigned short*)(ws + 4 * WMAT + 4 * TEN);
  unsigned short* vvb = (unsigned short*)(ws + 4 * WMAT + 5 * TEN);
  unsigned short* AO  = yq;  // yq fully consumed by pw(q) before attention writes

  // fused prep: dw-conv (z<96, with inline posconv for q,k) + cvt4 (z>=96)
  dw_kernel<<<dim3(8, 8, 112), 256, 0, stream>>>(
      query, key, value, pos,
      q_dw_w, k_dw_w, v_dw_w, q_dw_b, k_dw_b, v_dw_b,
      q_pw_w, k_pw_w, v_pw_w, proj_w, wq, wk, wv, wp,
      yq, yk, yv);

  pw_gemm_kernel<<<dim3(4, 4, 96), 256, 0, stream>>>(
      wq, wk, wv, yq, yk, yv, q_pw_b, k_pw_b, v_pw_b, qT, kT, vvb);

  attn_kernel<<<dim3(256), 512, 0, stream>>>(qT, kT, vvb, AO);

  final_gemm_kernel<<<dim3(4, 8, 32), 256, 0, stream>>>(AO, wp, proj_b, (float*)d_out);
}

// Round 12
// 254.213 us; speedup vs baseline: 1.0260x; 1.0260x over previous
//
#include <hip/hip_runtime.h>

typedef __attribute__((ext_vector_type(8))) short short8;
typedef __attribute__((ext_vector_type(4))) float float4v;
typedef __attribute__((ext_vector_type(16))) float float16v;
typedef __attribute__((ext_vector_type(4))) unsigned short ushort4v;

#define NB 32
#define NC 512
#define NL 512
#define NH 8
#define NDK 64

__device__ __forceinline__ unsigned short f2b(float f) {
  union { float f; unsigned int u; } v; v.f = f;
  unsigned int r = v.u + 0x7FFFu + ((v.u >> 16) & 1u);
  return (unsigned short)(r >> 16);
}

__device__ __forceinline__ unsigned int cvtpk(float lo, float hi) {
  unsigned int r;
  asm("v_cvt_pk_bf16_f32 %0, %1, %2" : "=v"(r) : "v"(lo), "v"(hi));
  return r;
}

__device__ __forceinline__ void gld16(const void* g, void* l) {
  __builtin_amdgcn_global_load_lds(
      (const __attribute__((address_space(1))) unsigned int*)g,
      (__attribute__((address_space(3))) unsigned int*)l, 16, 0, 0);
}

__device__ __forceinline__ float4v bmfma(short8 a, short8 b, float4v c) {
  return __builtin_amdgcn_mfma_f32_16x16x32_bf16(a, b, c, 0, 0, 0);
}

// ---- fused prep: depthwise conv(7) with inline posconv for q,k; plus -------
// ---- fp32->bf16 weight conversion absorbed as extra z-slices ---------------
// dw core: c64 x l64 tile, one barrier, 6144 independent blocks.
// gld16 staging: LDS dest is WAVE-UNIFORM base + lane*16 (m104), so every
// wave is fully active -- all 1344 cells (incl. pad f4==20 and OOB halo)
// issue gld16 with a CLAMPED global address. Pad garbage never read; OOB
// halo garbage zeroed in registers (wave-uniform branches on edge blocks).
// Stride 84 == 20 mod 32 keeps the 64-lane b128 compute reads conflict-free.
__global__ __launch_bounds__(256) void dw_kernel(
    const float* __restrict__ q, const float* __restrict__ k, const float* __restrict__ v,
    const float* __restrict__ pos,
    const float* __restrict__ qw, const float* __restrict__ kw, const float* __restrict__ vw,
    const float* __restrict__ qb2, const float* __restrict__ kb2, const float* __restrict__ vb,
    const float* __restrict__ cq, const float* __restrict__ ck,
    const float* __restrict__ cv, const float* __restrict__ cp,
    unsigned short* __restrict__ wq, unsigned short* __restrict__ wk,
    unsigned short* __restrict__ wv, unsigned short* __restrict__ wp,
    unsigned short* __restrict__ yq, unsigned short* __restrict__ yk,
    unsigned short* __restrict__ yv) {
  int z = blockIdx.z;
  int tid = threadIdx.x;
  if (z >= 96) {
    // ---- cvt4 job: fp32 -> bf16, 4 matrices of 512x512 ----
    int idx = (z - 96) * 64 + blockIdx.y * 8 + blockIdx.x;
    int m = idx >> 8, blk = idx & 255;
    const float* src = (m == 0) ? cq : (m == 1) ? ck : (m == 2) ? cv : cp;
    unsigned short* dst = (m == 0) ? wq : (m == 1) ? wk : (m == 2) ? wv : wp;
    int i = (blk * 256 + tid) * 4;
    float4v vv = *(const float4v*)(src + i);
    ushort4v o;
    o.x = f2b(vv.x); o.y = f2b(vv.y); o.z = f2b(vv.z); o.w = f2b(vv.w);
    *(ushort4v*)(dst + i) = o;
    return;
  }
  int t = z >> 5, b = z & 31;
  const float* x   = (t == 0) ? q  : (t == 1) ? k  : v;
  const float* dww = (t == 0) ? qw : (t == 1) ? kw : vw;
  const float* dwb = (t == 0) ? qb2 : (t == 1) ? kb2 : vb;
  unsigned short* yT = (t == 0) ? yq : (t == 1) ? yk : yv;
  int c0 = blockIdx.y * 64, l0 = blockIdx.x * 64;
  __shared__ __attribute__((aligned(16))) float xs[64 * 84];
#pragma unroll
  for (int it = 0; it < 6; ++it) {
    int idx = tid + 256 * it;
    if (idx < 1344) {
      int row = idx / 21, f4 = idx - row * 21;
      int l = l0 - 8 + f4 * 4;
      int lc = l < 0 ? 0 : (l > NL - 4 ? NL - 4 : l);
      gld16(x + ((size_t)b * NC + c0 + row) * NL + lc, xs + idx * 4);
    }
  }
  int cl = tid & 63;
  int llb = (tid >> 6) * 16;
  int c = c0 + cl;
  // hoisted independent work: taps, bias, inline posconv (hides under staging)
  float wt[7];
#pragma unroll
  for (int tt = 0; tt < 7; ++tt) wt[tt] = dww[c * 7 + tt];
  float bias0 = dwb[c];
  float addv[16];
  if (t < 2) {
    // addv[i] = dwb[c] + sum_tt pos[l0+llb+i+tt-3, c] * wt[tt]
    float pv[22];
#pragma unroll
    for (int j = 0; j < 22; ++j) {
      int ll = l0 + llb - 3 + j;
      pv[j] = ((unsigned)ll < (unsigned)NL) ? pos[(size_t)ll * NC + c] : 0.f;
    }
#pragma unroll
    for (int i = 0; i < 16; ++i) {
      float acc = bias0;
#pragma unroll
      for (int tt = 0; tt < 7; ++tt) acc += pv[i + tt] * wt[tt];
      addv[i] = acc;
    }
  } else {
#pragma unroll
    for (int i = 0; i < 16; ++i) addv[i] = bias0;
  }
  __syncthreads();
  // per-thread window: w[j] = x[l0 + llb - 4 + j], j = 0..23
  float w[24];
  const float4v* xr = (const float4v*)(xs + cl * 84 + llb + 4);
#pragma unroll
  for (int j = 0; j < 6; ++j) {
    float4v t4 = xr[j];
    w[4 * j] = t4.x; w[4 * j + 1] = t4.y; w[4 * j + 2] = t4.z; w[4 * j + 3] = t4.w;
  }
  // zero the OOB taps (clamped-load garbage); wave-uniform branches.
  if (blockIdx.x == 0 && llb == 0) {
    w[0] = 0.f; w[1] = 0.f; w[2] = 0.f; w[3] = 0.f;
  } else if (blockIdx.x == 7 && llb == 48) {
    w[20] = 0.f; w[21] = 0.f; w[22] = 0.f; w[23] = 0.f;
  }
#pragma unroll
  for (int i = 0; i < 16; ++i) {
    float acc = addv[i];
#pragma unroll
    for (int tt = 0; tt < 7; ++tt) acc += w[i + 1 + tt] * wt[tt];
    yT[((size_t)b * NL + l0 + llb + i) * NC + c] = f2b(acc);
  }
}

// ---- 128x128 MFMA GEMM core, BK=64, global-XOR-swizzled staging ------------
__device__ __forceinline__ void gemm_core_bk64(
    const unsigned short* __restrict__ A, const unsigned short* __restrict__ B,
    unsigned short* lA, unsigned short* lB, float4v acc[4][4], int m0, int n0) {
  int tid = threadIdx.x;
  int lane = tid & 63, quad = lane >> 4, l15 = lane & 15;
  int wave = tid >> 6, wr = wave >> 1, wc = wave & 1;
  const unsigned short* gA[4];
  const unsigned short* gB[4];
  unsigned short* dA[4];
  unsigned short* dB[4];
#pragma unroll
  for (int i = 0; i < 4; ++i) {
    int cc = tid + 256 * i;
    int row = cc >> 3;
    int gc = (cc & 7) ^ (row & 7);
    gA[i] = A + (size_t)(m0 + row) * 512 + gc * 8;
    gB[i] = B + (size_t)(n0 + row) * 512 + gc * 8;
    dA[i] = lA + cc * 8;
    dB[i] = lB + cc * 8;
  }
  for (int k0 = 0; k0 < 512; k0 += 64) {
#pragma unroll
    for (int i = 0; i < 4; ++i) gld16(gA[i] + k0, dA[i]);
#pragma unroll
    for (int i = 0; i < 4; ++i) gld16(gB[i] + k0, dB[i]);
    __syncthreads();
#pragma unroll
    for (int ks = 0; ks < 2; ++ks) {
      int sw = (ks * 4 + quad) ^ (l15 & 7);
      short8 af[4], bf[4];
#pragma unroll
      for (int mt = 0; mt < 4; ++mt)
        af[mt] = *(const short8*)(lA + (wr * 64 + mt * 16 + l15) * 64 + sw * 8);
#pragma unroll
      for (int nt = 0; nt < 4; ++nt)
        bf[nt] = *(const short8*)(lB + (wc * 64 + nt * 16 + l15) * 64 + sw * 8);
#pragma unroll
      for (int mt = 0; mt < 4; ++mt)
#pragma unroll
        for (int nt = 0; nt < 4; ++nt)
          acc[mt][nt] = bmfma(af[mt], bf[nt], acc[mt][nt]);
    }
    __syncthreads();
  }
}

// ---- fused pointwise GEMMs for q,k,v ---------------------------------------
// q output is pre-scaled by 0.125*log2(e) so attention can use exp2 directly.
// q/k epilogue: LDS transpose in [n][m] layout, XOR-swizzled m-index
// (scalar writes keep live ranges short -> ~108 VGPR).
// v epilogue: DIRECT scalar stores (R9 lesson: the LDS-transpose variant
// raised VGPR 108->124 and cost ~9us on this latency-bound GEMM).
__global__ __launch_bounds__(256) void pw_gemm_kernel(
    const unsigned short* __restrict__ wqm, const unsigned short* __restrict__ wkm,
    const unsigned short* __restrict__ wvm,
    const unsigned short* __restrict__ yq, const unsigned short* __restrict__ yk,
    const unsigned short* __restrict__ yv,
    const float* __restrict__ qb, const float* __restrict__ kb, const float* __restrict__ vb,
    unsigned short* __restrict__ qT, unsigned short* __restrict__ kT,
    unsigned short* __restrict__ vvo) {
  int z = blockIdx.z, t = z >> 5, b = z & 31;
  const unsigned short* W = (t == 0) ? wqm : (t == 1) ? wkm : wvm;
  const unsigned short* Y = ((t == 0) ? yq : (t == 1) ? yk : yv) + (size_t)b * NL * NC;
  const float* bias = (t == 0) ? qb : (t == 1) ? kb : vb;
  unsigned short* out = (t == 0) ? qT : (t == 1) ? kT : vvo;
  float oscale = (t == 0) ? 0.18033688011112042f : 1.0f;  // 0.125*log2(e) folded into q
  __shared__ __attribute__((aligned(16))) unsigned short buf[16384];
  unsigned short* lA = buf;
  unsigned short* lB = buf + 8192;
  int m0 = blockIdx.y * 128, n0 = blockIdx.x * 128;
  float4v acc[4][4];
#pragma unroll
  for (int i = 0; i < 4; ++i)
#pragma unroll
    for (int j = 0; j < 4; ++j) acc[i][j] = (float4v){0.f, 0.f, 0.f, 0.f};
  gemm_core_bk64(W, Y, lA, lB, acc, m0, n0);
  int tid = threadIdx.x;
  int lane = tid & 63, quad = lane >> 4, l15 = lane & 15;
  int wave = tid >> 6, wr = wave >> 1, wc = wave & 1;
  if (t < 2) {
    // transpose epilogue through LDS: scalar writes, XOR-swizzled m-index;
    // read side inverts with dc ^ (l&7).
#pragma unroll
    for (int mt = 0; mt < 4; ++mt) {
      int mloc = wr * 64 + mt * 16 + quad * 4;
#pragma unroll
      for (int nt = 0; nt < 4; ++nt) {
        int nloc = wc * 64 + nt * 16 + l15;
        int sx = (nloc & 7) << 3;
#pragma unroll
        for (int r = 0; r < 4; ++r) {
          int ml = mloc + r;
          buf[(ml >> 6) * 8192 + nloc * 64 + ((ml & 63) ^ sx)] =
              f2b((acc[mt][nt][r] + bias[m0 + ml]) * oscale);
        }
      }
    }
    __syncthreads();
#pragma unroll
    for (int it = 0; it < 8; ++it) {
      int cc = tid + it * 256;
      int hloc = cc >> 10, l = (cc >> 3) & 127, dc = cc & 7;
      short8 vd = *(const short8*)(buf + hloc * 8192 + l * 64 + ((dc ^ (l & 7)) << 3));
      *(short8*)(out + (((size_t)b * NH + (m0 >> 6) + hloc) * NL + n0 + l) * NDK + dc * 8) = vd;
    }
  } else {
#pragma unroll
    for (int mt = 0; mt < 4; ++mt)
#pragma unroll
      for (int nt = 0; nt < 4; ++nt) {
        int n = n0 + wc * 64 + nt * 16 + l15;
#pragma unroll
        for (int r = 0; r < 4; ++r) {
          int m = m0 + wr * 64 + mt * 16 + quad * 4 + r;
          out[((size_t)b * NC + m) * NL + n] = f2b(acc[mt][nt][r] + bias[m]);
        }
      }
  }
}

// ---- persistent attention, swapped-QK^T, P fully in-register ---------------
// Compute S^T = mfma(K,Q) so each lane owns one i-COLUMN; P packs to bf16
// in-register, halves exchange via shfl_xor(32), PV B-fragment built by
// per-half select -> NO P LDS buffer. Row sums: 16 lane-local adds + one
// shfl_xor(32). LDS = Kt+Vt = 128KB -> 512-thread 8-wave block, 2 waves/SIMD.
// R12: v_cvt_pk_bf16_f32 replaces 16 f2b (48 VALU -> 8 ops per jb; T12
// recipe, RNE rounding identical to f2b for positive finite p) and
// s_setprio(1) wraps the MFMA clusters (T5: +4-7% on attn-shaped kernels
// with phase-diverse waves, m191).
__global__ __launch_bounds__(512, 1) void attn_kernel(
    const unsigned short* __restrict__ qT,  // (B,H,L,DK)
    const unsigned short* __restrict__ kT,  // (B,H,L,DK)
    const unsigned short* __restrict__ vv,  // (B,C,L)
    unsigned short* __restrict__ AO) {      // (B,C,L)
  int bh = blockIdx.x, b = bh >> 3, h = bh & 7;
  int tid = threadIdx.x, lane = tid & 63;
  int l31 = lane & 31, lh = lane >> 5;
  int wave = tid >> 6;
  __shared__ __attribute__((aligned(16))) unsigned short Kt[512 * 64];  // [j][d] swz
  __shared__ __attribute__((aligned(16))) unsigned short Vt[64 * 512];  // [d][j] swz
  const unsigned short* qh = qT + (size_t)bh * NL * NDK;
  const unsigned short* kh = kT + (size_t)bh * NL * NDK;
  const unsigned short* vh = vv + ((size_t)b * NC + h * NDK) * NL;

  // one-time stage of all K and V (swizzle realized on the global side)
#pragma unroll
  for (int ii = 0; ii < 8; ++ii) {
    int cc = tid + 512 * ii;
    int row = cc >> 3, c = (cc & 7) ^ (row & 7);
    gld16(kh + (size_t)row * NDK + c * 8, &Kt[cc * 8]);
  }
#pragma unroll
  for (int ii = 0; ii < 8; ++ii) {
    int cc = tid + 512 * ii;
    int d = cc >> 6, pc = cc & 63;
    int c = (pc & ~7) | ((pc & 7) ^ (d & 7));
    gld16(vh + (size_t)d * NL + c * 8, &Vt[cc * 8]);
  }
  __syncthreads();  // only barrier in the kernel

#pragma unroll
  for (int iset = 0; iset < 2; ++iset) {
    int i0 = wave * 64 + iset * 32;
    // Q as B-operand: n = i = i0 + l31, k = d = s*16 + lh*8 + e
    short8 a[4];
#pragma unroll
    for (int s = 0; s < 4; ++s)
      a[s] = *(const short8*)(qh + (size_t)(i0 + l31) * NDK + s * 16 + lh * 8);
    float16v o0, o1;
#pragma unroll
    for (int r = 0; r < 16; ++r) { o0[r] = 0.f; o1[r] = 0.f; }
    float lsum = 0.f;

    for (int jb = 0; jb < 16; ++jb) {
      // S^T = mfma(K, Q): D[m=j][n=i]; lane owns column i, regs span 32 j
      float16v sacc;
#pragma unroll
      for (int r = 0; r < 16; ++r) sacc[r] = 0.f;
      __builtin_amdgcn_s_setprio(1);
#pragma unroll
      for (int s = 0; s < 4; ++s) {
        int cslot = (s * 2 + lh) ^ (l31 & 7);
        short8 kbf = *(const short8*)(&Kt[(size_t)(jb * 32 + l31) * 64 + cslot * 8]);
        sacc = __builtin_amdgcn_mfma_f32_32x32x16_bf16(kbf, a[s], sacc, 0, 0, 0);
      }
      __builtin_amdgcn_s_setprio(0);
      // p = exp2(s); per-lane row-sum partial (all 16 regs belong to col i)
      float p[16];
#pragma unroll
      for (int r = 0; r < 16; ++r) {
        p[r] = __builtin_amdgcn_exp2f(sacc[r]);
        lsum += p[r];
      }
      // pack to bf16 pairs (one v_cvt_pk_bf16_f32 each);
      // reg r holds j_local = (r&3)+8*(r>>2)+4*lh
      unsigned int c0 = cvtpk(p[0],  p[1]);   // j {0,1}+4lh
      unsigned int c1 = cvtpk(p[2],  p[3]);   // j {2,3}+4lh
      unsigned int c2 = cvtpk(p[4],  p[5]);   // j {8,9}+4lh
      unsigned int c3 = cvtpk(p[6],  p[7]);   // j {10,11}+4lh
      unsigned int c4 = cvtpk(p[8],  p[9]);   // j {16,17}+4lh
      unsigned int c5 = cvtpk(p[10], p[11]);  // j {18,19}+4lh
      unsigned int c6 = cvtpk(p[12], p[13]);  // j {24,25}+4lh
      unsigned int c7 = cvtpk(p[14], p[15]);  // j {26,27}+4lh
      unsigned int q0 = __shfl_xor(c0, 32);
      unsigned int q1 = __shfl_xor(c1, 32);
      unsigned int q2 = __shfl_xor(c2, 32);
      unsigned int q3 = __shfl_xor(c3, 32);
      unsigned int q4 = __shfl_xor(c4, 32);
      unsigned int q5 = __shfl_xor(c5, 32);
      unsigned int q6 = __shfl_xor(c6, 32);
      unsigned int q7 = __shfl_xor(c7, 32);
      // B-fragment for PV: lane needs k = j = js*16 + lh*8 + e
      union { unsigned int u[4]; short8 s8; } f0, f1;
      f0.u[0] = lh ? q2 : c0;  f0.u[1] = lh ? q3 : c1;
      f0.u[2] = lh ? c2 : q0;  f0.u[3] = lh ? c3 : q1;
      f1.u[0] = lh ? q6 : c4;  f1.u[1] = lh ? q7 : c5;
      f1.u[2] = lh ? c6 : q4;  f1.u[3] = lh ? c7 : q5;
      // O += V P^T : A = V[d][j] from Vt, B = frag (register-resident)
      __builtin_amdgcn_s_setprio(1);
#pragma unroll
      for (int js = 0; js < 2; ++js) {
        int g = jb * 4 + js * 2 + lh;
        int vc = (g & ~7) | ((g & 7) ^ (l31 & 7));
        short8 av0 = *(const short8*)(&Vt[(size_t)l31 * 512 + vc * 8]);
        short8 av1 = *(const short8*)(&Vt[(size_t)(32 + l31) * 512 + vc * 8]);
        short8 fb = js ? f1.s8 : f0.s8;
        o0 = __builtin_amdgcn_mfma_f32_32x32x16_bf16(av0, fb, o0, 0, 0, 0);
        o1 = __builtin_amdgcn_mfma_f32_32x32x16_bf16(av1, fb, o1, 0, 0, 0);
      }
      __builtin_amdgcn_s_setprio(0);
    }
    // full row sum for column i: own half + partner half
    float tot = lsum + __shfl_xor(lsum, 32);
    float li = __builtin_amdgcn_rcpf(tot);
#pragma unroll
    for (int r = 0; r < 16; ++r) {
      int dr = (r & 3) + 8 * (r >> 2) + 4 * lh;
      AO[((size_t)b * NC + h * NDK + dr) * NL + i0 + l31] = f2b(o0[r] * li);
      AO[((size_t)b * NC + h * NDK + 32 + dr) * NL + i0 + l31] = f2b(o1[r] * li);
    }
  }
}

// ---- final projection GEMM (fp32 out), M=64 x N=128, BK=32 -----------------
// 1024 blocks (4/CU co-resident), 12 KB LDS, 32-fp32 acc/thread. Swizzle for
// 4-chunk rows: phys = quad ^ ((row>>1)&3) -- 2-way = free (m136); staging
// source pre-swizzled, LDS dest linear (all threads active, R7 lesson).
__global__ __launch_bounds__(256) void final_gemm_kernel(
    const unsigned short* __restrict__ AO, const unsigned short* __restrict__ W,
    const float* __restrict__ bias, float* __restrict__ out) {
  int b = blockIdx.z;
  int m0 = blockIdx.y * 64, n0 = blockIdx.x * 128;
  __shared__ __attribute__((aligned(16))) unsigned short buf[6144];  // 12 KB
  unsigned short* lA = buf;          // 64 x 32
  unsigned short* lB = buf + 2048;   // 128 x 32
  const unsigned short* A = AO + (size_t)b * 512 * 512;
  int tid = threadIdx.x;
  int lane = tid & 63, quad = lane >> 4, l15 = lane & 15;
  int wave = tid >> 6;
  // staging assignments (cell = row*4 + physical chunk)
  int rowA = tid >> 2, pA = tid & 3;
  const unsigned short* gA = A + (size_t)(m0 + rowA) * 512 + (pA ^ ((rowA >> 1) & 3)) * 8;
  unsigned short* dA = lA + tid * 8;
  int ccB0 = tid, ccB1 = tid + 256;
  int rowB0 = ccB0 >> 2, rowB1 = ccB1 >> 2;
  const unsigned short* gB0 = W + (size_t)(n0 + rowB0) * 512 + ((ccB0 & 3) ^ ((rowB0 >> 1) & 3)) * 8;
  const unsigned short* gB1 = W + (size_t)(n0 + rowB1) * 512 + ((ccB1 & 3) ^ ((rowB1 >> 1) & 3)) * 8;
  unsigned short* dB0 = lB + ccB0 * 8;
  unsigned short* dB1 = lB + ccB1 * 8;
  float4v acc[4][2];
#pragma unroll
  for (int i = 0; i < 4; ++i)
#pragma unroll
    for (int j = 0; j < 2; ++j) acc[i][j] = (float4v){0.f, 0.f, 0.f, 0.f};
  int sA = (quad ^ ((l15 >> 1) & 3)) * 8;
  for (int k0 = 0; k0 < 512; k0 += 32) {
    gld16(gA + k0, dA);
    gld16(gB0 + k0, dB0);
    gld16(gB1 + k0, dB1);
    __syncthreads();
    short8 af[4], bf[2];
#pragma unroll
    for (int mt = 0; mt < 4; ++mt)
      af[mt] = *(const short8*)(lA + (mt * 16 + l15) * 32 + sA);
#pragma unroll
    for (int nt = 0; nt < 2; ++nt)
      bf[nt] = *(const short8*)(lB + (wave * 32 + nt * 16 + l15) * 32 + sA);
#pragma unroll
    for (int mt = 0; mt < 4; ++mt)
#pragma unroll
      for (int nt = 0; nt < 2; ++nt)
        acc[mt][nt] = bmfma(af[mt], bf[nt], acc[mt][nt]);
    __syncthreads();
  }
#pragma unroll
  for (int mt = 0; mt < 4; ++mt)
#pragma unroll
    for (int nt = 0; nt < 2; ++nt) {
      int n = n0 + wave * 32 + nt * 16 + l15;
      float bn = bias[n];
#pragma unroll
      for (int r = 0; r < 4; ++r) {
        int m = m0 + mt * 16 + quad * 4 + r;
        out[((size_t)b * 512 + m) * 512 + n] = acc[mt][nt][r] + bn;
      }
    }
}

extern "C" void kernel_launch(void* const* d_in, const int* in_sizes, int n_in,
                              void* d_out, int out_size, void* d_ws, size_t ws_size,
                              hipStream_t stream) {
  (void)in_sizes; (void)n_in; (void)out_size; (void)ws_size;
  const float* query  = (const float*)d_in[0];
  const float* key    = (const float*)d_in[1];
  const float* value  = (const float*)d_in[2];
  const float* pos    = (const float*)d_in[3];
  const float* proj_w = (const float*)d_in[4];
  const float* proj_b = (const float*)d_in[5];
  const float* q_dw_w = (const float*)d_in[6];
  const float* q_dw_b = (const float*)d_in[7];
  const float* q_pw_w = (const float*)d_in[8];
  const float* q_pw_b = (const float*)d_in[9];
  const float* k_dw_w = (const float*)d_in[10];
  const float* k_dw_b = (const float*)d_in[11];
  const float* k_pw_w = (const float*)d_in[12];
  const float* k_pw_b = (const float*)d_in[13];
  const float* v_dw_w = (const float*)d_in[14];
  const float* v_dw_b = (const float*)d_in[15];
  const float* v_pw_w = (const float*)d_in[16];
  const float* v_pw_b = (const float*)d_in[17];

  char* ws = (char*)d_ws;
  const size_t WMAT = (size_t)512 * 512 * 2;     // 512 KB
  const size_t TEN  = (size_t)NB * NC * NL * 2;  // 16 MB
  unsigned short* wq  = (unsigned short*)(ws);
  unsigned short* wk  = (unsigned short*)(ws + WMAT);
  unsigned short* wv  = (unsigned short*)(ws + 2 * WMAT);
  unsigned short* wp  = (unsigned short*)(ws + 3 * WMAT);
  unsigned short* yq  = (unsigned short*)(ws + 4 * WMAT);
  unsigned short* yk  = (unsigned short*)(ws + 4 * WMAT + TEN);
  unsigned short* yv  = (unsigned short*)(ws + 4 * WMAT + 2 * TEN);
  unsigned short* qT  = (unsigned short*)(ws + 4 * WMAT + 3 * TEN);
  unsigned short* kT  = (unsigned short*)(ws + 4 * WMAT + 4 * TEN);
  unsigned short* vvb = (unsigned short*)(ws + 4 * WMAT + 5 * TEN);
  unsigned short* AO  = yq;  // yq fully consumed by pw(q) before attention writes

  // fused prep: dw-conv (z<96, with inline posconv for q,k) + cvt4 (z>=96)
  dw_kernel<<<dim3(8, 8, 112), 256, 0, stream>>>(
      query, key, value, pos,
      q_dw_w, k_dw_w, v_dw_w, q_dw_b, k_dw_b, v_dw_b,
      q_pw_w, k_pw_w, v_pw_w, proj_w, wq, wk, wv, wp,
      yq, yk, yv);

  pw_gemm_kernel<<<dim3(4, 4, 96), 256, 0, stream>>>(
      wq, wk, wv, yq, yk, yv, q_pw_b, k_pw_b, v_pw_b, qT, kT, vvb);

  attn_kernel<<<dim3(256), 512, 0, stream>>>(qT, kT, vvb, AO);

  final_gemm_kernel<<<dim3(4, 8, 32), 256, 0, stream>>>(AO, wp, proj_b, (float*)d_out);
}